// Round 1
// 173.838 us; speedup vs baseline: 1.0601x; 1.0601x over previous
//
#include <hip/hip_runtime.h>
#include <hip/hip_bf16.h>
#include <math.h>

#define L1_     5248
#define LENRRC_ 129
#define TSTART_ 65
#define NWIN_   5120
#define SWZ(m) ((m) + ((m) >> 3))     // stride-8 reads -> stride-9 -> conflict-free

typedef __attribute__((ext_vector_type(8))) short s16x8;   // 8 bf16 lanes (4 VGPRs)
typedef __attribute__((ext_vector_type(4))) float f32x4;   // MFMA accumulator

__device__ inline ushort bf16_rne(float x) {
    unsigned xb = __float_as_uint(x);
    return (ushort)((xb + 0x7fffu + ((xb >> 16) & 1u)) >> 16);
}

__device__ inline float wave_sum(float v) {
    #pragma unroll
    for (int m = 32; m > 0; m >>= 1) v += __shfl_xor(v, m, 64);
    return v;
}
__device__ inline float wave_max(float v) {
    #pragma unroll
    for (int m = 32; m > 0; m >>= 1) v = fmaxf(v, __shfl_xor(v, m, 64));
    return v;
}

// ---------- fused pack: x->bf16 | W1^T bf16 | W2^T bf16 | (fallback: z=bias) ----------
__global__ __launch_bounds__(256) void pack_k(const float* __restrict__ x,
        const float* __restrict__ W1, const float* __restrict__ W2,
        const float* __restrict__ benc,
        ushort* __restrict__ xb, ushort* __restrict__ w1t, ushort* __restrict__ w2t,
        float* __restrict__ z)
{
    __shared__ ushort tile[64][70];
    const int blk = blockIdx.x, tid = threadIdx.x;
    if (blk < 3072) {                                  // pack x (1024x3072), x4 floats
        int i = blk * 256 + tid;
        float4 v = ((const float4*)x)[i];
        ushort4 h;
        h.x = bf16_rne(v.x); h.y = bf16_rne(v.y);
        h.z = bf16_rne(v.z); h.w = bf16_rne(v.w);
        ((ushort4*)xb)[i] = h;
    } else if (blk < 3840) {                           // transpose W1 / W2 into bf16
        const float* W; ushort* T; int K, N, n0, k0;
        if (blk < 3456) {
            int idx = blk - 3072;                      // grid (8,48)
            W = W1; T = w1t; K = 3072; N = 512;
            n0 = (idx & 7) * 64; k0 = (idx >> 3) * 64;
        } else {
            int idx = blk - 3456;                      // grid (48,8)
            W = W2; T = w2t; K = 512; N = 3072;
            n0 = (idx % 48) * 64; k0 = (idx / 48) * 64;
        }
        const int cr = tid >> 4, cc = (tid & 15) * 4;
        #pragma unroll
        for (int i = 0; i < 4; ++i) {
            int kk = i * 16 + cr;
            float4 v = *(const float4*)&W[(size_t)(k0 + kk) * N + n0 + cc];
            tile[kk][cc]     = bf16_rne(v.x);
            tile[kk][cc + 1] = bf16_rne(v.y);
            tile[kk][cc + 2] = bf16_rne(v.z);
            tile[kk][cc + 3] = bf16_rne(v.w);
        }
        __syncthreads();
        #pragma unroll
        for (int i = 0; i < 4; ++i) {
            int nn = i * 16 + cr;
            ushort4 h;
            h.x = tile[cc][nn]; h.y = tile[cc + 1][nn];
            h.z = tile[cc + 2][nn]; h.w = tile[cc + 3][nn];
            *(ushort4*)&T[(size_t)(n0 + nn) * K + k0 + cc] = h;
        }
    } else {                                           // fallback only: init z with bias
        int i = (blk - 3840) * 256 + tid;              // 524288 total
        z[i] = benc[i & 511];
    }
}

// ---------- gemm1: single bf16, 64x128xBK64, SK=8 -> per-split partial panels ----------
__global__ __launch_bounds__(256) void gemm1_k(const ushort* __restrict__ Ab,
        const ushort* __restrict__ Bb, float* __restrict__ C, int M, int N, int K,
        int partial)
{
    __shared__ ushort Asl[64 * 72];     // 9.2 KB
    __shared__ ushort Bsl[128 * 72];    // 18.4 KB
    const int tid = threadIdx.x;
    const int lane = tid & 63, wave = tid >> 6;
    const int wm = (wave >> 1) * 32, wn = (wave & 1) * 64;
    const int m0 = blockIdx.y * 64, n0 = blockIdx.x * 128;
    const int kch = K / 8, kbeg = blockIdx.z * kch, kend = kbeg + kch;
    const int fm = lane & 15, q = lane >> 4;
    f32x4 acc[2][4] = {};

    for (int kt = kbeg; kt < kend; kt += 64) {
        #pragma unroll
        for (int i = 0; i < 2; ++i) {                  // A 64x64
            int c = i * 256 + tid;
            int row = c >> 3, k8 = (c & 7) * 8;
            *(uint4*)&Asl[row * 72 + k8] =
                *(const uint4*)&Ab[(size_t)(m0 + row) * K + kt + k8];
        }
        #pragma unroll
        for (int i = 0; i < 4; ++i) {                  // B 128x64
            int c = i * 256 + tid;
            int row = c >> 3, k8 = (c & 7) * 8;
            *(uint4*)&Bsl[row * 72 + k8] =
                *(const uint4*)&Bb[(size_t)(n0 + row) * K + kt + k8];
        }
        __syncthreads();
        #pragma unroll
        for (int ks = 0; ks < 2; ++ks) {
            s16x8 a[2], b[4];
            #pragma unroll
            for (int mf = 0; mf < 2; ++mf)
                a[mf] = *(const s16x8*)&Asl[(wm + mf * 16 + fm) * 72 + ks * 32 + q * 8];
            #pragma unroll
            for (int nf = 0; nf < 4; ++nf)
                b[nf] = *(const s16x8*)&Bsl[(wn + nf * 16 + fm) * 72 + ks * 32 + q * 8];
            #pragma unroll
            for (int mf = 0; mf < 2; ++mf)
                #pragma unroll
                for (int nf = 0; nf < 4; ++nf)
                    acc[mf][nf] = __builtin_amdgcn_mfma_f32_16x16x32_bf16(a[mf], b[nf], acc[mf][nf], 0, 0, 0);
        }
        __syncthreads();
    }

    if (partial) {                                     // deterministic per-split panel
        float* Cs = C + (size_t)blockIdx.z * ((size_t)M * N);
        #pragma unroll
        for (int mf = 0; mf < 2; ++mf)
            #pragma unroll
            for (int nf = 0; nf < 4; ++nf)
                #pragma unroll
                for (int r = 0; r < 4; ++r) {
                    int m = m0 + wm + mf * 16 + q * 4 + r;
                    int n = n0 + wn + nf * 16 + fm;
                    Cs[(size_t)m * N + n] = acc[mf][nf][r];
                }
    } else {                                           // fallback: atomic accumulate
        #pragma unroll
        for (int mf = 0; mf < 2; ++mf)
            #pragma unroll
            for (int nf = 0; nf < 4; ++nf)
                #pragma unroll
                for (int r = 0; r < 4; ++r) {
                    int m = m0 + wm + mf * 16 + q * 4 + r;
                    int n = n0 + wn + nf * 16 + fm;
                    atomicAdd(&C[(size_t)m * N + n], acc[mf][nf][r]);
                }
    }
}

// ---------- gemm2: single bf16, 64x64xBK64, direct + bias, fused PAPR loss ----------
__global__ __launch_bounds__(256) void gemm2_k(const ushort* __restrict__ Ab,
        const ushort* __restrict__ Bb, const float* __restrict__ bias,
        const float* __restrict__ papr, float* __restrict__ C,
        float* __restrict__ out_loss, int M, int N, int K)
{
    __shared__ ushort Asl[64 * 72];
    __shared__ ushort Bsl[64 * 72];
    __shared__ float red[4];
    const int tid = threadIdx.x;
    const int lane = tid & 63, wave = tid >> 6;
    const int wm = (wave >> 1) * 32, wn = (wave & 1) * 32;
    const int m0 = blockIdx.y * 64, n0 = blockIdx.x * 64;
    const int fm = lane & 15, q = lane >> 4;
    f32x4 acc[2][2] = {};

    for (int kt = 0; kt < K; kt += 64) {
        #pragma unroll
        for (int i = 0; i < 2; ++i) {
            int c = i * 256 + tid;
            int row = c >> 3, k8 = (c & 7) * 8;
            *(uint4*)&Asl[row * 72 + k8] =
                *(const uint4*)&Ab[(size_t)(m0 + row) * K + kt + k8];
            *(uint4*)&Bsl[row * 72 + k8] =
                *(const uint4*)&Bb[(size_t)(n0 + row) * K + kt + k8];
        }
        __syncthreads();
        #pragma unroll
        for (int ks = 0; ks < 2; ++ks) {
            s16x8 a[2], b[2];
            #pragma unroll
            for (int mf = 0; mf < 2; ++mf)
                a[mf] = *(const s16x8*)&Asl[(wm + mf * 16 + fm) * 72 + ks * 32 + q * 8];
            #pragma unroll
            for (int nf = 0; nf < 2; ++nf)
                b[nf] = *(const s16x8*)&Bsl[(wn + nf * 16 + fm) * 72 + ks * 32 + q * 8];
            #pragma unroll
            for (int mf = 0; mf < 2; ++mf)
                #pragma unroll
                for (int nf = 0; nf < 2; ++nf)
                    acc[mf][nf] = __builtin_amdgcn_mfma_f32_16x16x32_bf16(a[mf], b[nf], acc[mf][nf], 0, 0, 0);
        }
        __syncthreads();
    }

    #pragma unroll
    for (int mf = 0; mf < 2; ++mf)
        #pragma unroll
        for (int nf = 0; nf < 2; ++nf)
            #pragma unroll
            for (int r = 0; r < 4; ++r) {
                int m = m0 + wm + mf * 16 + q * 4 + r;
                int n = n0 + wn + nf * 16 + fm;
                C[(size_t)m * N + n] = acc[mf][nf][r] + bias[n];
            }

    if (blockIdx.x == 0 && blockIdx.y == 0) {          // fused PAPR loss
        float s = 0.f;
        for (int i = tid; i < 1024; i += 256) { float v = papr[i] - 8.f; s += v > 0.f ? v : 0.f; }
        s = wave_sum(s);
        if (lane == 0) red[wave] = s;
        __syncthreads();
        if (tid == 0) *out_loss = (red[0] + red[1] + red[2] + red[3]) * (1.f / 1024.f);
    }
}

// ---------- megakernel: one block per batch row, whole signal chain in LDS ----------
__global__ __launch_bounds__(256) void mega_k(const float* __restrict__ z,
        const float* __restrict__ benc,
        const float* __restrict__ rrc, const float* __restrict__ awgn,
        const int* __restrict__ slocp, ushort* __restrict__ y5b,
        float* __restrict__ papr, float* __restrict__ out_papr, int nsp)
{
    __shared__ float  zl[512];
    __shared__ float2 frfi[8][32];
    __shared__ float2 trti[672];       // [0..15]=0 | data [16..655] | [656..671]=0 ; reused as dp/dm after P6
    __shared__ float  hl[132];
    __shared__ float  csl[16], ssl[16];
    __shared__ float2 cs64[64];
    __shared__ float2 gcs[130];
    __shared__ float  dxr[SWZ(L1_ - 1) + 1];
    __shared__ float2 wrli[512];
    __shared__ float  red[4], red2[4];

    const int b = blockIdx.x, tid = threadIdx.x;
    const int lane = tid & 63, wv = tid >> 6;
    const int sloc = *slocp;

    // ---- tables ----
    if (tid < 64) {
        float ang = 0.09817477042468103f * (float)tid;   // 2pi/64
        float s, c; sincosf(ang, &s, &c);
        cs64[tid] = make_float2(c, s);
    }
    if (tid >= 64 && tid < 80) {
        int t = tid - 64;
        float ang = 1.9634954084936207f * (float)t;      // 2pi*5/16
        float s, c; sincosf(ang, &s, &c);
        csl[t] = 1.4142135623730951f * c; ssl[t] = 1.4142135623730951f * s;
    }
    if (tid >= 96 && tid < 128) {                        // trti zero pads
        int t = tid - 96;
        int idx = (t < 16) ? t : (640 + t);              // [0..15] and [656..671]
        trti[idx] = make_float2(0.f, 0.f);
    }
    for (int e = tid; e < LENRRC_; e += 256) hl[e] = rrc[e];

    // ---- z row: bias + sum of split-K partial panels (or prereduced fallback) ----
    float v0, v1;
    if (nsp) {
        v0 = benc[tid]; v1 = benc[tid + 256];
        const float* zp = z + (size_t)b * 512;
        #pragma unroll
        for (int s = 0; s < 8; ++s) {
            v0 += zp[(size_t)s * 524288 + tid];
            v1 += zp[(size_t)s * 524288 + tid + 256];
        }
    } else {
        v0 = z[(size_t)b * 512 + tid];
        v1 = z[(size_t)b * 512 + tid + 256];
    }
    __syncthreads();

    // ---- gcs: carrier folded into RRC taps ----
    if (tid < LENRRC_) {
        int neg = (16 - (tid & 15)) & 15;                // (-d) & 15
        gcs[tid] = make_float2(hl[tid] * csl[neg], hl[tid] * ssl[neg]);
    }

    // ---- power norm (single pass: S, Q; ddof=1) ----
    {
        float S = wave_sum(v0 + v1);
        float Q = wave_sum(v0 * v0 + v1 * v1);
        if (lane == 0) { red[wv] = S; red2[wv] = Q; }
    }
    __syncthreads();
    {
        float S = red[0] + red[1] + red[2] + red[3];
        float Q = red2[0] + red2[1] + red2[2] + red2[3];
        float mean = S * (1.f / 512.f);
        float var = (Q - S * mean) * (1.f / 511.f);
        float inv = 1.f / (sqrtf(var) + 1e-8f);
        zl[tid] = (v0 - mean) * inv; zl[tid + 256] = (v1 - mean) * inv;
    }
    __syncthreads();

    // ---- P1: DFT32 (+fftshift folded) ----
    {
        int s = tid >> 5, kk = tid & 31;
        int kk2 = (kk + 16) & 31;
        float sr = 0.f, si = 0.f;
        int t2 = 0;
        for (int q = 0; q < 32; ++q) {
            float2 w = cs64[2 * t2];
            float2 c = *(const float2*)&zl[(s * 32 + q) * 2];
            sr += c.x * w.x + c.y * w.y;                 // * e^{-i ang}
            si += c.y * w.x - c.x * w.y;
            t2 = (t2 + kk2) & 31;
        }
        frfi[s][kk] = make_float2(sr * 0.1767766952966369f, si * 0.1767766952966369f);
    }
    __syncthreads();

    // ---- P2: IDFT64 + CP, n/(n+32) fold: w[k,n+32] = (-1)^{sloc+k} w[k,n] ----
    {
        int s = tid >> 5, n = tid & 31;                  // 256 items, each -> pair (n, n+32)
        float er = 0.f, ei = 0.f, or_ = 0.f, oi = 0.f;   // k-even / k-odd partial sums
        int t = (sloc * n) & 63;
        for (int k = 0; k < 32; k += 2) {
            float2 w = cs64[t];
            float2 f = frfi[s][k];
            er += f.x * w.x - f.y * w.y;                 // * e^{+i ang}
            ei += f.y * w.x + f.x * w.y;
            t = (t + n) & 63;
            w = cs64[t];
            f = frfi[s][k + 1];
            or_ += f.x * w.x - f.y * w.y;
            oi  += f.y * w.x + f.x * w.y;
            t = (t + n) & 63;
        }
        float sgn = (sloc & 1) ? -1.f : 1.f;
        float dr0 = (er + or_) * 0.125f, di0 = (ei + oi) * 0.125f;        // d[n]
        float dr1 = sgn * (er - or_) * 0.125f, di1 = sgn * (ei - oi) * 0.125f; // d[n+32]
        int base = s * 80;                               // padded layout: data at [base+32 .. base+95]
        trti[base + 32 + n] = make_float2(dr0, di0);
        trti[base + 64 + n] = make_float2(dr1, di1);
        if (n >= 16) trti[base + n] = make_float2(dr1, di1);   // CP: old n'=n+32 in [48,64)
    }
    __syncthreads();

    // ---- P3: upsample x8 + RRC polyphase + carrier -> dxr (swizzled), sumsq ----
    float ss = 0.f;
    for (int a = tid; a < 656; a += 256) {
        float accr[8] = {}, acci[8] = {};
        #pragma unroll 4
        for (int d = 0; d < 16; ++d) {
            float2 tv = trti[16 + a - d];                // zero-padded: no bounds check
            #pragma unroll
            for (int r = 0; r < 8; ++r) {
                float h = hl[r + 8 * d];
                accr[r] += tv.x * h; acci[r] += tv.y * h;
            }
        }
        {   // d=16, tap 128, r=0 only
            float2 tv = trti[a];                         // 16 + a - 16
            float h = hl[128];
            accr[0] += tv.x * h; acci[0] += tv.y * h;
        }
        int cb = (a & 1) * 8;
        #pragma unroll
        for (int r = 0; r < 8; ++r) {
            float v = accr[r] * csl[cb + r] - acci[r] * ssl[cb + r];
            dxr[SWZ(a * 8 + r)] = v;
            ss += v * v;
        }
    }
    ss = wave_sum(ss);
    if (lane == 0) red[wv] = ss;
    __syncthreads();
    float thr = 1.2f * sqrtf((red[0] + red[1] + red[2] + red[3]) / (float)L1_);
    __syncthreads();

    // ---- P5: clip + PAPR window stats + AWGN (in place) ----
    float pmax = 0.f, psum = 0.f;
    for (int i = tid; i < L1_; i += 256) {
        float x = dxr[SWZ(i)];
        float ax = fabsf(x);
        float over = ax - thr; over = over > 0.f ? over : 0.f;
        float y = (1.f - over / (ax + 1e-8f)) * x;
        if (i >= TSTART_ && i < TSTART_ + NWIN_) { float p = y * y; psum += p; pmax = fmaxf(pmax, p); }
        dxr[SWZ(i)] = y + awgn[(size_t)b * L1_ + i];
    }
    psum = wave_sum(psum); pmax = wave_max(pmax);
    if (lane == 0) { red[wv] = psum; red2[wv] = pmax; }
    __syncthreads();
    if (tid == 0) {
        float sum = red[0] + red[1] + red[2] + red[3];
        float mx = fmaxf(fmaxf(red2[0], red2[1]), fmaxf(red2[2], red2[3]));
        float pdb = 10.f * log10f(mx / (sum / (float)NWIN_));
        papr[b] = pdb;
        out_papr[b] = pdb;
    }
    __syncthreads();     // also guarantees all P5 dxr writes visible before P6

    // ---- P6: matched RRC filter, carrier folded into gcs taps ----
    #pragma unroll
    for (int j0 = 0; j0 < 2; ++j0) {
        int j = j0 * 256 + tid;
        int s = j >> 6, n = j & 63;
        int T = s * 80 + n + 32;                         // Nf/8
        int base = 9 * T;                                // SWZ(Nf)
        int db = 0;
        float ar = 0.f, ai = 0.f;
        for (int e = 0; e < 16; ++e) {
            #pragma unroll
            for (int u = 0; u < 8; ++u) {
                int off = (u == 0) ? 0 : (u + 1);
                float v = dxr[base - off];
                float2 g = gcs[db + u];
                ar += v * g.x; ai += v * g.y;
            }
            base -= 9; db += 8;
        }
        { float v = dxr[base]; float2 g = gcs[128]; ar += v * g.x; ai += v * g.y; }
        float sr = (n & 1) ? -ar : ar;                   // odd n: taps negate
        float si = (n & 1) ? ai : -ai;                   // wil = -(sign*ai)
        wrli[j] = make_float2(sr, si);
    }
    __syncthreads();

    // ---- P7a: fold d[n] +/- d[n+32] into trti (dead after P3): dp=[0..255], dm=[256..511] ----
    {
        int s = tid >> 5, n = tid & 31;
        float2 d0 = wrli[s * 64 + n];
        float2 d1 = wrli[s * 64 + n + 32];
        trti[s * 32 + n]       = make_float2(d0.x + d1.x, d0.y + d1.y);
        trti[256 + s * 32 + n] = make_float2(d0.x - d1.x, d0.y - d1.y);
    }
    __syncthreads();

    // ---- P7: DFT64 -> band select -> fftshift, halved via n/(n+32) fold ----
    {
        int s = tid >> 5, kk = tid & 31;
        int f = sloc + kk;
        const float2* dsel = &trti[((f & 1) ? 256 : 0) + s * 32];
        float vr = 0.f, vi = 0.f;
        int t = 0;
        for (int n = 0; n < 32; ++n) {
            float2 w = cs64[t];
            float2 d = dsel[n];
            vr += d.x * w.x + d.y * w.y;                 // * e^{-i ang}
            vi += d.y * w.x - d.x * w.y;
            t = (t + f) & 63;
        }
        int ksh = (kk + 16) & 31;
        frfi[s][ksh] = make_float2(vr * 0.125f, vi * 0.125f);
    }
    __syncthreads();

    // ---- P8: IDFT32 -> y5 single bf16 plane ----
    {
        int s = tid >> 5, q2 = tid & 31;
        float ur = 0.f, ui = 0.f;
        int t2 = 0;
        for (int k = 0; k < 32; ++k) {
            float2 w = cs64[2 * t2];
            float2 f = frfi[s][k];
            ur += f.x * w.x - f.y * w.y;                 // * e^{+i ang}
            ui += f.y * w.x + f.x * w.y;
            t2 = (t2 + q2) & 31;
        }
        ur *= 0.1767766952966369f; ui *= 0.1767766952966369f;
        ushort2 hv; hv.x = bf16_rne(ur); hv.y = bf16_rne(ui);
        *(ushort2*)&y5b[(size_t)b * 512 + (s * 32 + q2) * 2] = hv;
    }
}

extern "C" void kernel_launch(void* const* d_in, const int* in_sizes, int n_in,
                              void* d_out, int out_size, void* d_ws, size_t ws_size,
                              hipStream_t stream) {
    const float* x    = (const float*)d_in[0];
    const float* Wenc = (const float*)d_in[1];
    const float* benc = (const float*)d_in[2];
    const float* Wdec = (const float*)d_in[3];
    const float* bdec = (const float*)d_in[4];
    const float* rrc  = (const float*)d_in[5];
    const float* awgn = (const float*)d_in[6];
    const int* sloc   = (const int*)d_in[7];
    float* out = (float*)d_out;

    char* wsb = (char*)d_ws;
    ushort* xb   = (ushort*)wsb;                     wsb += (size_t)1024 * 3072 * 2;
    ushort* w1t  = (ushort*)wsb;                     wsb += (size_t)512 * 3072 * 2;
    ushort* w2t  = (ushort*)wsb;                     wsb += (size_t)3072 * 512 * 2;
    ushort* y5b  = (ushort*)wsb;                     wsb += (size_t)1024 * 512 * 2;
    float*  papr = (float*)wsb;                      wsb += 1024 * 4;
    float*  zbuf = (float*)wsb;                      // partial: 8 x 1024x512 f32 (16.8 MB)
                                                     // fallback: 1024x512 f32 (2.1 MB)
    size_t head = (size_t)((char*)zbuf - (char*)d_ws);
    int partial = (ws_size >= head + (size_t)8 * 1024 * 512 * 4) ? 1 : 0;

    float* out_papr = out + (size_t)1024 * 3072;
    float* out_loss = out_papr + 1024;

    pack_k<<<partial ? 3840 : 5888, 256, 0, stream>>>(x, Wenc, Wdec, benc, xb, w1t, w2t, zbuf);
    gemm1_k<<<dim3(4, 16, 8), 256, 0, stream>>>(xb, w1t, zbuf, 1024, 512, 3072, partial);
    mega_k<<<1024, 256, 0, stream>>>(zbuf, benc, rrc, awgn, sloc, y5b, papr, out_papr,
                                     partial ? 8 : 0);
    gemm2_k<<<dim3(48, 16, 1), 256, 0, stream>>>(y5b, w2t, bdec, papr, out, out_loss, 1024, 3072, 512);
}

// Round 2
// 147.213 us; speedup vs baseline: 1.2518x; 1.1809x over previous
//
#include <hip/hip_runtime.h>
#include <hip/hip_bf16.h>
#include <math.h>

#define L1_     5248
#define LENRRC_ 129
#define TSTART_ 65
#define NWIN_   5120
#define SWZ(m) ((m) + ((m) >> 3))     // stride-8 reads -> stride-9 -> conflict-free

typedef __attribute__((ext_vector_type(8))) short s16x8;   // 8 bf16 lanes (4 VGPRs)
typedef __attribute__((ext_vector_type(4))) float f32x4;   // MFMA accumulator

__device__ inline ushort bf16_rne(float x) {
    unsigned xb = __float_as_uint(x);
    return (ushort)((xb + 0x7fffu + ((xb >> 16) & 1u)) >> 16);
}

__device__ inline float wave_sum(float v) {
    #pragma unroll
    for (int m = 32; m > 0; m >>= 1) v += __shfl_xor(v, m, 64);
    return v;
}
__device__ inline float wave_max(float v) {
    #pragma unroll
    for (int m = 32; m > 0; m >>= 1) v = fmaxf(v, __shfl_xor(v, m, 64));
    return v;
}

// direct global->LDS 16B staging (dest = wave-uniform base + lane*16)
__device__ inline void gl_lds16(const void* g, void* l) {
    __builtin_amdgcn_global_load_lds(
        (const __attribute__((address_space(1))) unsigned int*)g,
        (__attribute__((address_space(3))) unsigned int*)l, 16, 0, 0);
}

// ---------- fused pack: x->bf16 | W1^T bf16 | W2^T bf16 | (fallback: z=bias) ----------
__global__ __launch_bounds__(256) void pack_k(const float* __restrict__ x,
        const float* __restrict__ W1, const float* __restrict__ W2,
        const float* __restrict__ benc,
        ushort* __restrict__ xb, ushort* __restrict__ w1t, ushort* __restrict__ w2t,
        float* __restrict__ z)
{
    __shared__ ushort tile[64][70];
    const int blk = blockIdx.x, tid = threadIdx.x;
    if (blk < 3072) {                                  // pack x (1024x3072), x4 floats
        int i = blk * 256 + tid;
        float4 v = ((const float4*)x)[i];
        ushort4 h;
        h.x = bf16_rne(v.x); h.y = bf16_rne(v.y);
        h.z = bf16_rne(v.z); h.w = bf16_rne(v.w);
        ((ushort4*)xb)[i] = h;
    } else if (blk < 3840) {                           // transpose W1 / W2 into bf16
        const float* W; ushort* T; int K, N, n0, k0;
        if (blk < 3456) {
            int idx = blk - 3072;                      // grid (8,48)
            W = W1; T = w1t; K = 3072; N = 512;
            n0 = (idx & 7) * 64; k0 = (idx >> 3) * 64;
        } else {
            int idx = blk - 3456;                      // grid (48,8)
            W = W2; T = w2t; K = 512; N = 3072;
            n0 = (idx % 48) * 64; k0 = (idx / 48) * 64;
        }
        const int cr = tid >> 4, cc = (tid & 15) * 4;
        #pragma unroll
        for (int i = 0; i < 4; ++i) {
            int kk = i * 16 + cr;
            float4 v = *(const float4*)&W[(size_t)(k0 + kk) * N + n0 + cc];
            tile[kk][cc]     = bf16_rne(v.x);
            tile[kk][cc + 1] = bf16_rne(v.y);
            tile[kk][cc + 2] = bf16_rne(v.z);
            tile[kk][cc + 3] = bf16_rne(v.w);
        }
        __syncthreads();
        #pragma unroll
        for (int i = 0; i < 4; ++i) {
            int nn = i * 16 + cr;
            ushort4 h;
            h.x = tile[cc][nn]; h.y = tile[cc + 1][nn];
            h.z = tile[cc + 2][nn]; h.w = tile[cc + 3][nn];
            *(ushort4*)&T[(size_t)(n0 + nn) * K + k0 + cc] = h;
        }
    } else {                                           // fallback only: init z with bias
        int i = (blk - 3840) * 256 + tid;              // 524288 total
        z[i] = benc[i & 511];
    }
}

// ---------- gemm1: 64x128xBK64, global_load_lds + XOR-swizzle, SK=8 partial panels ----------
__global__ __launch_bounds__(256) void gemm1_k(const ushort* __restrict__ Ab,
        const ushort* __restrict__ Bb, float* __restrict__ C, int M, int N, int K,
        int partial)
{
    __shared__ __attribute__((aligned(16))) ushort Asl[64 * 64];    // 8 KB, linear
    __shared__ __attribute__((aligned(16))) ushort Bsl[128 * 64];   // 16 KB, linear
    const int tid = threadIdx.x;
    const int lane = tid & 63, wave = tid >> 6;
    const int wm = (wave >> 1) * 32, wn = (wave & 1) * 64;
    const int m0 = blockIdx.y * 64, n0 = blockIdx.x * 128;
    const int kch = K / 8, kbeg = blockIdx.z * kch, kend = kbeg + kch;
    const int fm = lane & 15, q = lane >> 4;
    f32x4 acc[2][4] = {};

    // per-lane staging coords: chunk c -> (row, kb) with kb inverse-swizzled,
    // so linear LDS dest holds the XOR-swizzled layout (rule 21: both-sides)
    int arow[2], akb[2], brow[4], bkb[4];
    #pragma unroll
    for (int j = 0; j < 2; ++j) {
        int c = ((wave * 2 + j) << 6) + lane;
        arow[j] = c >> 3; akb[j] = (c & 7) ^ (arow[j] & 7);
    }
    #pragma unroll
    for (int j = 0; j < 4; ++j) {
        int c = ((wave * 4 + j) << 6) + lane;
        brow[j] = c >> 3; bkb[j] = (c & 7) ^ (brow[j] & 7);
    }

    for (int kt = kbeg; kt < kend; kt += 64) {
        #pragma unroll
        for (int j = 0; j < 2; ++j)                    // A 64x64 = 8 segments
            gl_lds16(&Ab[(size_t)(m0 + arow[j]) * K + kt + akb[j] * 8],
                     &Asl[(wave * 2 + j) << 9]);
        #pragma unroll
        for (int j = 0; j < 4; ++j)                    // B 128x64 = 16 segments
            gl_lds16(&Bb[(size_t)(n0 + brow[j]) * K + kt + bkb[j] * 8],
                     &Bsl[(wave * 4 + j) << 9]);
        __syncthreads();                               // vmcnt(0) drain inserted here
        #pragma unroll
        for (int ks = 0; ks < 2; ++ks) {
            s16x8 a[2], b[4];
            #pragma unroll
            for (int mf = 0; mf < 2; ++mf) {
                int r = wm + mf * 16 + fm;
                a[mf] = *(const s16x8*)&Asl[(r << 6) + ((((ks << 2) + q) ^ (r & 7)) << 3)];
            }
            #pragma unroll
            for (int nf = 0; nf < 4; ++nf) {
                int r = wn + nf * 16 + fm;
                b[nf] = *(const s16x8*)&Bsl[(r << 6) + ((((ks << 2) + q) ^ (r & 7)) << 3)];
            }
            #pragma unroll
            for (int mf = 0; mf < 2; ++mf)
                #pragma unroll
                for (int nf = 0; nf < 4; ++nf)
                    acc[mf][nf] = __builtin_amdgcn_mfma_f32_16x16x32_bf16(a[mf], b[nf], acc[mf][nf], 0, 0, 0);
        }
        __syncthreads();
    }

    if (partial) {                                     // deterministic per-split panel
        float* Cs = C + (size_t)blockIdx.z * ((size_t)M * N);
        #pragma unroll
        for (int mf = 0; mf < 2; ++mf)
            #pragma unroll
            for (int nf = 0; nf < 4; ++nf)
                #pragma unroll
                for (int r = 0; r < 4; ++r) {
                    int m = m0 + wm + mf * 16 + q * 4 + r;
                    int n = n0 + wn + nf * 16 + fm;
                    Cs[(size_t)m * N + n] = acc[mf][nf][r];
                }
    } else {                                           // fallback: atomic accumulate
        #pragma unroll
        for (int mf = 0; mf < 2; ++mf)
            #pragma unroll
            for (int nf = 0; nf < 4; ++nf)
                #pragma unroll
                for (int r = 0; r < 4; ++r) {
                    int m = m0 + wm + mf * 16 + q * 4 + r;
                    int n = n0 + wn + nf * 16 + fm;
                    atomicAdd(&C[(size_t)m * N + n], acc[mf][nf][r]);
                }
    }
}

// ---------- gemm2: 64x64xBK64, global_load_lds + XOR-swizzle, + bias, fused PAPR loss ----------
__global__ __launch_bounds__(256) void gemm2_k(const ushort* __restrict__ Ab,
        const ushort* __restrict__ Bb, const float* __restrict__ bias,
        const float* __restrict__ papr, float* __restrict__ C,
        float* __restrict__ out_loss, int M, int N, int K)
{
    __shared__ __attribute__((aligned(16))) ushort Asl[64 * 64];
    __shared__ __attribute__((aligned(16))) ushort Bsl[64 * 64];
    __shared__ float red[4];
    const int tid = threadIdx.x;
    const int lane = tid & 63, wave = tid >> 6;
    const int wm = (wave >> 1) * 32, wn = (wave & 1) * 32;
    const int m0 = blockIdx.y * 64, n0 = blockIdx.x * 64;
    const int fm = lane & 15, q = lane >> 4;
    f32x4 acc[2][2] = {};

    int srow[2], skb[2];
    #pragma unroll
    for (int j = 0; j < 2; ++j) {
        int c = ((wave * 2 + j) << 6) + lane;
        srow[j] = c >> 3; skb[j] = (c & 7) ^ (srow[j] & 7);
    }

    for (int kt = 0; kt < K; kt += 64) {
        #pragma unroll
        for (int j = 0; j < 2; ++j) {
            gl_lds16(&Ab[(size_t)(m0 + srow[j]) * K + kt + skb[j] * 8],
                     &Asl[(wave * 2 + j) << 9]);
            gl_lds16(&Bb[(size_t)(n0 + srow[j]) * K + kt + skb[j] * 8],
                     &Bsl[(wave * 2 + j) << 9]);
        }
        __syncthreads();
        #pragma unroll
        for (int ks = 0; ks < 2; ++ks) {
            s16x8 a[2], b[2];
            #pragma unroll
            for (int mf = 0; mf < 2; ++mf) {
                int r = wm + mf * 16 + fm;
                a[mf] = *(const s16x8*)&Asl[(r << 6) + ((((ks << 2) + q) ^ (r & 7)) << 3)];
            }
            #pragma unroll
            for (int nf = 0; nf < 2; ++nf) {
                int r = wn + nf * 16 + fm;
                b[nf] = *(const s16x8*)&Bsl[(r << 6) + ((((ks << 2) + q) ^ (r & 7)) << 3)];
            }
            #pragma unroll
            for (int mf = 0; mf < 2; ++mf)
                #pragma unroll
                for (int nf = 0; nf < 2; ++nf)
                    acc[mf][nf] = __builtin_amdgcn_mfma_f32_16x16x32_bf16(a[mf], b[nf], acc[mf][nf], 0, 0, 0);
        }
        __syncthreads();
    }

    #pragma unroll
    for (int mf = 0; mf < 2; ++mf)
        #pragma unroll
        for (int nf = 0; nf < 2; ++nf)
            #pragma unroll
            for (int r = 0; r < 4; ++r) {
                int m = m0 + wm + mf * 16 + q * 4 + r;
                int n = n0 + wn + nf * 16 + fm;
                C[(size_t)m * N + n] = acc[mf][nf][r] + bias[n];
            }

    if (blockIdx.x == 0 && blockIdx.y == 0) {          // fused PAPR loss
        float s = 0.f;
        for (int i = tid; i < 1024; i += 256) { float v = papr[i] - 8.f; s += v > 0.f ? v : 0.f; }
        s = wave_sum(s);
        if (lane == 0) red[wave] = s;
        __syncthreads();
        if (tid == 0) *out_loss = (red[0] + red[1] + red[2] + red[3]) * (1.f / 1024.f);
    }
}

// ---------- megakernel: one block per batch row, whole signal chain in LDS ----------
__global__ __launch_bounds__(256, 4) void mega_k(const float* __restrict__ z,
        const float* __restrict__ benc,
        const float* __restrict__ rrc, const float* __restrict__ awgn,
        const int* __restrict__ slocp, ushort* __restrict__ y5b,
        float* __restrict__ papr, float* __restrict__ out_papr, int nsp)
{
    __shared__ float  zl[512];
    __shared__ float2 frfi[8][32];
    __shared__ float2 trti[672];       // [0..15]=0 | data [16..655] | [656..671]=0 ; reused as dp/dm after P6
    __shared__ float  hl[132];
    __shared__ float  csl[16], ssl[16];
    __shared__ float2 cs64[64];
    __shared__ float2 gcs[130];
    __shared__ float  dxr[SWZ(L1_ - 1) + 1];
    __shared__ float2 wrli[512];
    __shared__ float  red[4], red2[4];

    const int b = blockIdx.x, tid = threadIdx.x;
    const int lane = tid & 63, wv = tid >> 6;
    const int sloc = *slocp;

    // ---- tables ----
    if (tid < 64) {
        float ang = 0.09817477042468103f * (float)tid;   // 2pi/64
        float s, c; sincosf(ang, &s, &c);
        cs64[tid] = make_float2(c, s);
    }
    if (tid >= 64 && tid < 80) {
        int t = tid - 64;
        float ang = 1.9634954084936207f * (float)t;      // 2pi*5/16
        float s, c; sincosf(ang, &s, &c);
        csl[t] = 1.4142135623730951f * c; ssl[t] = 1.4142135623730951f * s;
    }
    if (tid >= 96 && tid < 128) {                        // trti zero pads
        int t = tid - 96;
        int idx = (t < 16) ? t : (640 + t);              // [0..15] and [656..671]
        trti[idx] = make_float2(0.f, 0.f);
    }
    for (int e = tid; e < LENRRC_; e += 256) hl[e] = rrc[e];

    // ---- z row: bias + sum of split-K partial panels (or prereduced fallback) ----
    float v0, v1;
    if (nsp) {
        v0 = benc[tid]; v1 = benc[tid + 256];
        const float* zp = z + (size_t)b * 512;
        #pragma unroll
        for (int s = 0; s < 8; ++s) {
            v0 += zp[(size_t)s * 524288 + tid];
            v1 += zp[(size_t)s * 524288 + tid + 256];
        }
    } else {
        v0 = z[(size_t)b * 512 + tid];
        v1 = z[(size_t)b * 512 + tid + 256];
    }
    __syncthreads();

    // ---- gcs: carrier folded into RRC taps ----
    if (tid < LENRRC_) {
        int neg = (16 - (tid & 15)) & 15;                // (-d) & 15
        gcs[tid] = make_float2(hl[tid] * csl[neg], hl[tid] * ssl[neg]);
    }

    // ---- power norm (single pass: S, Q; ddof=1) ----
    {
        float S = wave_sum(v0 + v1);
        float Q = wave_sum(v0 * v0 + v1 * v1);
        if (lane == 0) { red[wv] = S; red2[wv] = Q; }
    }
    __syncthreads();
    {
        float S = red[0] + red[1] + red[2] + red[3];
        float Q = red2[0] + red2[1] + red2[2] + red2[3];
        float mean = S * (1.f / 512.f);
        float var = (Q - S * mean) * (1.f / 511.f);
        float inv = 1.f / (sqrtf(var) + 1e-8f);
        zl[tid] = (v0 - mean) * inv; zl[tid + 256] = (v1 - mean) * inv;
    }
    __syncthreads();

    // ---- P1: DFT32 (+fftshift folded) ----
    {
        int s = tid >> 5, kk = tid & 31;
        int kk2 = (kk + 16) & 31;
        float sr = 0.f, si = 0.f;
        int t2 = 0;
        #pragma unroll 4
        for (int q = 0; q < 32; ++q) {
            float2 w = cs64[2 * t2];
            float2 c = *(const float2*)&zl[(s * 32 + q) * 2];
            sr += c.x * w.x + c.y * w.y;                 // * e^{-i ang}
            si += c.y * w.x - c.x * w.y;
            t2 = (t2 + kk2) & 31;
        }
        frfi[s][kk] = make_float2(sr * 0.1767766952966369f, si * 0.1767766952966369f);
    }
    __syncthreads();

    // ---- P2: IDFT64 + CP, n/(n+32) fold: w[k,n+32] = (-1)^{sloc+k} w[k,n] ----
    {
        int s = tid >> 5, n = tid & 31;                  // 256 items, each -> pair (n, n+32)
        float er = 0.f, ei = 0.f, or_ = 0.f, oi = 0.f;   // k-even / k-odd partial sums
        int t = (sloc * n) & 63;
        #pragma unroll 2
        for (int k = 0; k < 32; k += 2) {
            float2 w = cs64[t];
            float2 f = frfi[s][k];
            er += f.x * w.x - f.y * w.y;                 // * e^{+i ang}
            ei += f.y * w.x + f.x * w.y;
            t = (t + n) & 63;
            w = cs64[t];
            f = frfi[s][k + 1];
            or_ += f.x * w.x - f.y * w.y;
            oi  += f.y * w.x + f.x * w.y;
            t = (t + n) & 63;
        }
        float sgn = (sloc & 1) ? -1.f : 1.f;
        float dr0 = (er + or_) * 0.125f, di0 = (ei + oi) * 0.125f;        // d[n]
        float dr1 = sgn * (er - or_) * 0.125f, di1 = sgn * (ei - oi) * 0.125f; // d[n+32]
        int base = s * 80;                               // padded layout: data at [base+32 .. base+95]
        trti[base + 32 + n] = make_float2(dr0, di0);
        trti[base + 64 + n] = make_float2(dr1, di1);
        if (n >= 16) trti[base + n] = make_float2(dr1, di1);   // CP: old n'=n+32 in [48,64)
    }
    __syncthreads();

    // ---- P3: upsample x8 + RRC polyphase + carrier -> dxr (swizzled), sumsq ----
    float ss = 0.f;
    for (int a = tid; a < 656; a += 256) {
        float accr[8] = {}, acci[8] = {};
        #pragma unroll 4
        for (int d = 0; d < 16; ++d) {
            float2 tv = trti[16 + a - d];                // zero-padded: no bounds check
            #pragma unroll
            for (int r = 0; r < 8; ++r) {
                float h = hl[r + 8 * d];
                accr[r] += tv.x * h; acci[r] += tv.y * h;
            }
        }
        {   // d=16, tap 128, r=0 only
            float2 tv = trti[a];                         // 16 + a - 16
            float h = hl[128];
            accr[0] += tv.x * h; acci[0] += tv.y * h;
        }
        int cb = (a & 1) * 8;
        #pragma unroll
        for (int r = 0; r < 8; ++r) {
            float v = accr[r] * csl[cb + r] - acci[r] * ssl[cb + r];
            dxr[SWZ(a * 8 + r)] = v;
            ss += v * v;
        }
    }
    ss = wave_sum(ss);
    if (lane == 0) red[wv] = ss;
    __syncthreads();
    float thr = 1.2f * sqrtf((red[0] + red[1] + red[2] + red[3]) / (float)L1_);
    __syncthreads();

    // ---- P5: clip + PAPR window stats + AWGN (in place), float4 x4-wide ----
    float pmax = 0.f, psum = 0.f;
    {
        const float4* ag = (const float4*)&awgn[(size_t)b * L1_];
        for (int ii = tid; ii < 1312; ii += 256) {       // 1312*4 = 5248
            float4 aw = ag[ii];
            int i = ii * 4;
            #pragma unroll
            for (int e = 0; e < 4; ++e) {
                int idx = i + e;
                float x = dxr[SWZ(idx)];
                float ax = fabsf(x);
                float over = fmaxf(ax - thr, 0.f);
                float y = (1.f - over / (ax + 1e-8f)) * x;
                if (idx >= TSTART_ && idx < TSTART_ + NWIN_) {
                    float p = y * y; psum += p; pmax = fmaxf(pmax, p);
                }
                float awv = (e == 0) ? aw.x : (e == 1) ? aw.y : (e == 2) ? aw.z : aw.w;
                dxr[SWZ(idx)] = y + awv;
            }
        }
    }
    psum = wave_sum(psum); pmax = wave_max(pmax);
    if (lane == 0) { red[wv] = psum; red2[wv] = pmax; }
    __syncthreads();
    if (tid == 0) {
        float sum = red[0] + red[1] + red[2] + red[3];
        float mx = fmaxf(fmaxf(red2[0], red2[1]), fmaxf(red2[2], red2[3]));
        float pdb = 10.f * log10f(mx / (sum / (float)NWIN_));
        papr[b] = pdb;
        out_papr[b] = pdb;
    }
    __syncthreads();     // also guarantees all P5 dxr writes visible before P6

    // ---- P6: matched RRC filter, both j-halves in ONE loop (share gcs reads) ----
    {
        int s = tid >> 6, n = tid & 63;
        int T0 = s * 80 + n + 32;                        // j = tid
        int base0 = 9 * T0;
        int base1 = 9 * (T0 + 320);                      // j = tid + 256 (s+4, same n)
        float ar0 = 0.f, ai0 = 0.f, ar1 = 0.f, ai1 = 0.f;
        int db = 0;
        #pragma unroll 2
        for (int e = 0; e < 16; ++e) {
            #pragma unroll
            for (int u = 0; u < 8; ++u) {
                int off = (u == 0) ? 0 : (u + 1);
                float2 g = gcs[db + u];
                float va = dxr[base0 - off];
                float vb = dxr[base1 - off];
                ar0 += va * g.x; ai0 += va * g.y;
                ar1 += vb * g.x; ai1 += vb * g.y;
            }
            base0 -= 9; base1 -= 9; db += 8;
        }
        {
            float2 g = gcs[128];
            float va = dxr[base0], vb = dxr[base1];
            ar0 += va * g.x; ai0 += va * g.y;
            ar1 += vb * g.x; ai1 += vb * g.y;
        }
        bool odd = (n & 1);
        wrli[tid]       = make_float2(odd ? -ar0 : ar0, odd ? ai0 : -ai0);
        wrli[tid + 256] = make_float2(odd ? -ar1 : ar1, odd ? ai1 : -ai1);
    }
    __syncthreads();

    // ---- P7a: fold d[n] +/- d[n+32] into trti (dead after P3): dp=[0..255], dm=[256..511] ----
    {
        int s = tid >> 5, n = tid & 31;
        float2 d0 = wrli[s * 64 + n];
        float2 d1 = wrli[s * 64 + n + 32];
        trti[s * 32 + n]       = make_float2(d0.x + d1.x, d0.y + d1.y);
        trti[256 + s * 32 + n] = make_float2(d0.x - d1.x, d0.y - d1.y);
    }
    __syncthreads();

    // ---- P7: DFT64 -> band select -> fftshift, halved via n/(n+32) fold ----
    {
        int s = tid >> 5, kk = tid & 31;
        int f = sloc + kk;
        const float2* dsel = &trti[((f & 1) ? 256 : 0) + s * 32];
        float vr = 0.f, vi = 0.f;
        int t = 0;
        #pragma unroll 4
        for (int n = 0; n < 32; ++n) {
            float2 w = cs64[t];
            float2 d = dsel[n];
            vr += d.x * w.x + d.y * w.y;                 // * e^{-i ang}
            vi += d.y * w.x - d.x * w.y;
            t = (t + f) & 63;
        }
        int ksh = (kk + 16) & 31;
        frfi[s][ksh] = make_float2(vr * 0.125f, vi * 0.125f);
    }
    __syncthreads();

    // ---- P8: IDFT32 -> y5 single bf16 plane ----
    {
        int s = tid >> 5, q2 = tid & 31;
        float ur = 0.f, ui = 0.f;
        int t2 = 0;
        #pragma unroll 4
        for (int k = 0; k < 32; ++k) {
            float2 w = cs64[2 * t2];
            float2 f = frfi[s][k];
            ur += f.x * w.x - f.y * w.y;                 // * e^{+i ang}
            ui += f.y * w.x + f.x * w.y;
            t2 = (t2 + q2) & 31;
        }
        ur *= 0.1767766952966369f; ui *= 0.1767766952966369f;
        ushort2 hv; hv.x = bf16_rne(ur); hv.y = bf16_rne(ui);
        *(ushort2*)&y5b[(size_t)b * 512 + (s * 32 + q2) * 2] = hv;
    }
}

extern "C" void kernel_launch(void* const* d_in, const int* in_sizes, int n_in,
                              void* d_out, int out_size, void* d_ws, size_t ws_size,
                              hipStream_t stream) {
    const float* x    = (const float*)d_in[0];
    const float* Wenc = (const float*)d_in[1];
    const float* benc = (const float*)d_in[2];
    const float* Wdec = (const float*)d_in[3];
    const float* bdec = (const float*)d_in[4];
    const float* rrc  = (const float*)d_in[5];
    const float* awgn = (const float*)d_in[6];
    const int* sloc   = (const int*)d_in[7];
    float* out = (float*)d_out;

    char* wsb = (char*)d_ws;
    ushort* xb   = (ushort*)wsb;                     wsb += (size_t)1024 * 3072 * 2;
    ushort* w1t  = (ushort*)wsb;                     wsb += (size_t)512 * 3072 * 2;
    ushort* w2t  = (ushort*)wsb;                     wsb += (size_t)3072 * 512 * 2;
    ushort* y5b  = (ushort*)wsb;                     wsb += (size_t)1024 * 512 * 2;
    float*  papr = (float*)wsb;                      wsb += 1024 * 4;
    float*  zbuf = (float*)wsb;                      // partial: 8 x 1024x512 f32 (16.8 MB)
                                                     // fallback: 1024x512 f32 (2.1 MB)
    size_t head = (size_t)((char*)zbuf - (char*)d_ws);
    int partial = (ws_size >= head + (size_t)8 * 1024 * 512 * 4) ? 1 : 0;

    float* out_papr = out + (size_t)1024 * 3072;
    float* out_loss = out_papr + 1024;

    pack_k<<<partial ? 3840 : 5888, 256, 0, stream>>>(x, Wenc, Wdec, benc, xb, w1t, w2t, zbuf);
    gemm1_k<<<dim3(4, 16, 8), 256, 0, stream>>>(xb, w1t, zbuf, 1024, 512, 3072, partial);
    mega_k<<<1024, 256, 0, stream>>>(zbuf, benc, rrc, awgn, sloc, y5b, papr, out_papr,
                                     partial ? 8 : 0);
    gemm2_k<<<dim3(48, 16, 1), 256, 0, stream>>>(y5b, w2t, bdec, papr, out, out_loss, 1024, 3072, 512);
}